// Round 1
// baseline (46.854 us; speedup 1.0000x reference)
//
#include <hip/hip_runtime.h>

// Problem constants (fixed by reference setup_inputs)
constexpr int Bn = 16, Hn = 128, Wn = 128, Cn = 64;
constexpr int NPIX = Bn * Hn * Wn;                 // 262144
constexpr int THREADS_PER_PIX = Cn / 4;            // 16 (float4 per thread)
constexpr int TOTAL_THREADS = NPIX * THREADS_PER_PIX;

__global__ __launch_bounds__(256) void cartpool_kernel(const float* __restrict__ x,
                                                       float* __restrict__ out) {
    const int gid = blockIdx.x * blockDim.x + threadIdx.x;
    const int pix = gid >> 4;            // pixel index
    if (pix >= NPIX) return;
    const int c4  = (gid & 15) << 2;     // channel offset (0,4,...,60)

    const int w = pix & (Wn - 1);
    const int h = (pix >> 7) & (Hn - 1);
    const int b = pix >> 14;

    // exp of 9 neighbors x 4 channels; OOB -> exp(0)=1 (zero padding included in softmax)
    float e[9][4];
    #pragma unroll
    for (int p = 0; p < 9; ++p) {
        const int di = p / 3, dj = p % 3;
        const int hh = h + di - 1;
        const int ww = w + dj - 1;
        const bool ok = ((unsigned)hh < (unsigned)Hn) && ((unsigned)ww < (unsigned)Wn);
        float4 v = make_float4(0.f, 0.f, 0.f, 0.f);
        if (ok) {
            v = *reinterpret_cast<const float4*>(
                x + ((((size_t)b * Hn + hh) * Wn + ww) << 6) + c4);
        }
        e[p][0] = __expf(v.x);
        e[p][1] = __expf(v.y);
        e[p][2] = __expf(v.z);
        e[p][3] = __expf(v.w);
    }

    // wx = [0,1,2,0,1,2,0,1,2], wy = [0,0,0,1,1,1,2,2,2]
    float ax[4], ay[4];
    #pragma unroll
    for (int q = 0; q < 4; ++q) {
        float S = 0.f;
        #pragma unroll
        for (int p = 0; p < 9; ++p) S += e[p][q];
        const float sx = e[1][q] + e[4][q] + e[7][q] + 2.f * (e[2][q] + e[5][q] + e[8][q]);
        const float sy = e[3][q] + e[4][q] + e[5][q] + 2.f * (e[6][q] + e[7][q] + e[8][q]);
        const float inv = __builtin_amdgcn_rcpf(S);     // v_rcp_f32, ~1 ulp approx
        ax[q] = (sx * inv - 1.f + (float)w) * (1.f / Wn);
        ay[q] = (sy * inv - 1.f + (float)h) * (1.f / Hn);
    }

    float* ob = out + (size_t)pix * (2 * Cn);
    *reinterpret_cast<float4*>(ob + c4)      = make_float4(ax[0], ax[1], ax[2], ax[3]);
    *reinterpret_cast<float4*>(ob + Cn + c4) = make_float4(ay[0], ay[1], ay[2], ay[3]);
}

extern "C" void kernel_launch(void* const* d_in, const int* in_sizes, int n_in,
                              void* d_out, int out_size, void* d_ws, size_t ws_size,
                              hipStream_t stream) {
    const float* x = (const float*)d_in[0];
    float* out = (float*)d_out;
    const int block = 256;
    const int grid = (TOTAL_THREADS + block - 1) / block;   // 16384
    cartpool_kernel<<<grid, block, 0, stream>>>(x, out);
}